// Round 7
// baseline (553.420 us; speedup 1.0000x reference)
//
#include <hip/hip_runtime.h>

#define N_NODES 100000
#define N_EDGES 20000
#define N_INC   1600000
#define NFEAT   256
#define NCLASS  64

#define ELOC 2500            // edges per range (e&7)
#define NLOC 12500           // nodes per range (n&7)
#define BCAP 201728          // per-bucket capacity (mean 200K + ~4 sigma, 64B-aligned)
#define EPB  8               // blocks per bucket in hist/fill
#define LCAP 192             // per-block LDS staging per bucket in k_bucket

typedef int v4i __attribute__((ext_vector_type(4)));

// ============ phase 1: split incidences into 8 edge- and 8 node-buckets ====
// edge-bucket (key e&7): payload (n<<12)|(e>>3)   n:17b, e>>3:12b
// node-bucket (key n&7): payload (e<<14)|(n>>3)   e:15b, n>>3:14b
// Only bulk cursor reservation atomics (~25K total), no histograms.
__global__ __launch_bounds__(256) void k_bucket(const int* __restrict__ nidx,
                                                const int* __restrict__ eidx,
                                                unsigned int* __restrict__ ebkt,
                                                unsigned int* __restrict__ nbkt,
                                                int* __restrict__ bcur) {
    __shared__ unsigned int stage[16][LCAP];
    __shared__ int lcnt[16];
    __shared__ int gbase[16];
    const int t = threadIdx.x;
    if (t < 16) lcnt[t] = 0;
    __syncthreads();

    const int base = blockIdx.x * 1024 + t * 4;
    if (base < N_INC) {
        const v4i e4 = __builtin_nontemporal_load((const v4i*)&eidx[base]);
        const v4i n4 = __builtin_nontemporal_load((const v4i*)&nidx[base]);
        const int es[4] = {e4.x, e4.y, e4.z, e4.w};
        const int ns[4] = {n4.x, n4.y, n4.z, n4.w};
        #pragma unroll
        for (int q = 0; q < 4; ++q) {
            const int e = es[q], n = ns[q];
            {
                const int b = e & 7;
                const unsigned int pay = ((unsigned int)n << 12) | (unsigned int)(e >> 3);
                const int pos = atomicAdd(&lcnt[b], 1);
                if (pos < LCAP) stage[b][pos] = pay;
                else ebkt[(size_t)b * BCAP + atomicAdd(&bcur[b], 1)] = pay;
            }
            {
                const int b = 8 + (n & 7);
                const unsigned int pay = ((unsigned int)e << 14) | (unsigned int)(n >> 3);
                const int pos = atomicAdd(&lcnt[b], 1);
                if (pos < LCAP) stage[b][pos] = pay;
                else nbkt[(size_t)(b - 8) * BCAP + atomicAdd(&bcur[b], 1)] = pay;
            }
        }
    }
    __syncthreads();
    if (t < 16) gbase[t] = atomicAdd(&bcur[t], min(lcnt[t], LCAP));
    __syncthreads();
    #pragma unroll 1
    for (int k = 0; k < 16; ++k) {
        const int cnt = min(lcnt[k], LCAP);
        const int gb  = gbase[k];
        unsigned int* dst = (k < 8) ? &ebkt[(size_t)k * BCAP]
                                    : &nbkt[(size_t)(k - 8) * BCAP];
        for (int i = t; i < cnt; i += 256) dst[gb + i] = stage[k][i];
    }
}

// ============ per-(bucket,block) LDS histogram → u16 per-block hists =======
__global__ __launch_bounds__(256) void k_hist(const unsigned int* __restrict__ bkt,
                                              const int* __restrict__ bcur,
                                              int cur_off,
                                              unsigned short* __restrict__ hist,
                                              int SZ, unsigned int mask) {
    extern __shared__ unsigned int h[];
    const int r = blockIdx.x & 7, b = blockIdx.x >> 3;
    const int t = threadIdx.x;
    for (int i = t; i < SZ; i += 256) h[i] = 0;
    __syncthreads();
    const int cnt = bcur[cur_off + r];
    const int sz  = (cnt + EPB - 1) / EPB;
    const int lo  = b * sz, hi = min(lo + sz, cnt);
    const unsigned int* B = &bkt[(size_t)r * BCAP];
    for (int i = lo + t; i < hi; i += 256)
        atomicAdd(&h[B[i] & mask], 1u);
    __syncthreads();
    unsigned short* H = &hist[(size_t)(r * EPB + b) * SZ];
    for (int i = t; i < SZ; i += 256) H[i] = (unsigned short)h[i];
}

// ============ per-counter exclusive prefix over the EPB block hists ========
__global__ __launch_bounds__(256) void k_colscan(unsigned short* __restrict__ hist,
                                                 int* __restrict__ cnt_perm, int SZ) {
    const int g = blockIdx.x * 256 + threadIdx.x;
    if (g >= 8 * SZ) return;
    const int r = g / SZ, i = g - r * SZ;
    unsigned short* H = hist + (size_t)r * EPB * SZ + i;
    unsigned int run = 0;
    #pragma unroll
    for (int b = 0; b < EPB; ++b) {
        const unsigned int v = H[(size_t)b * SZ];
        H[(size_t)b * SZ] = (unsigned short)run;
        run += v;
    }
    cnt_perm[g] = (int)run;
}

// ============ single-block exclusive scan (int4), offsets only =============
__global__ __launch_bounds__(1024) void k_scan(const int* __restrict__ cnt,
                                               int* __restrict__ off, int n) {
    __shared__ int part[1024];
    const int t = threadIdx.x;
    const int chunk = ((n / 4 + 1023) / 1024) * 4;
    const int lo = min(t * chunk, n);
    const int hi = min(lo + chunk, n);
    int s = 0;
    for (int i = lo; i < hi; i += 4) {
        const int4 v = *(const int4*)&cnt[i];
        s += v.x + v.y + v.z + v.w;
    }
    part[t] = s;
    __syncthreads();
    for (int d = 1; d < 1024; d <<= 1) {
        int v = (t >= d) ? part[t - d] : 0;
        __syncthreads();
        part[t] += v;
        __syncthreads();
    }
    int run = (t == 0) ? 0 : part[t - 1];
    for (int i = lo; i < hi; i += 4) {
        const int4 v = *(const int4*)&cnt[i];
        int4 o;
        o.x = run; run += v.x;
        o.y = run; run += v.y;
        o.z = run; run += v.z;
        o.w = run; run += v.w;
        *(int4*)&off[i] = o;
    }
}

// ============ fills: LDS cursors = off + per-block prefix; LDS atomics only
__global__ __launch_bounds__(256) void k_fill3n(const unsigned int* __restrict__ nbkt,
                                                const int* __restrict__ bcur,
                                                const unsigned short* __restrict__ nhist,
                                                const int* __restrict__ noff,
                                                unsigned short* __restrict__ ninc) {
    __shared__ unsigned int lb[NLOC];
    const int r = blockIdx.x & 7, b = blockIdx.x >> 3;
    const int t = threadIdx.x;
    const unsigned short* H = &nhist[(size_t)(r * EPB + b) * NLOC];
    const int* O = &noff[r * NLOC];
    for (int i = t; i < NLOC; i += 256) lb[i] = (unsigned int)O[i] + H[i];
    __syncthreads();
    const int cnt = bcur[8 + r];
    const int sz  = (cnt + EPB - 1) / EPB;
    const int lo  = b * sz, hi = min(lo + sz, cnt);
    const unsigned int* B = &nbkt[(size_t)r * BCAP];
    for (int i = lo + t; i < hi; i += 256) {
        const unsigned int u = B[i];
        const unsigned int pos = atomicAdd(&lb[u & 0x3FFFu], 1u);
        ninc[pos] = (unsigned short)(u >> 14);
    }
}

__global__ __launch_bounds__(256) void k_fill3e(const unsigned int* __restrict__ ebkt,
                                                const int* __restrict__ bcur,
                                                const unsigned short* __restrict__ ehist,
                                                const int* __restrict__ eoff,
                                                int* __restrict__ einc) {
    __shared__ unsigned int lb[ELOC];
    const int r = blockIdx.x & 7, b = blockIdx.x >> 3;
    const int t = threadIdx.x;
    const unsigned short* H = &ehist[(size_t)(r * EPB + b) * ELOC];
    const int* O = &eoff[r * ELOC];
    for (int i = t; i < ELOC; i += 256) lb[i] = (unsigned int)O[i] + H[i];
    __syncthreads();
    const int cnt = bcur[r];
    const int sz  = (cnt + EPB - 1) / EPB;
    const int lo  = b * sz, hi = min(lo + sz, cnt);
    const unsigned int* B = &ebkt[(size_t)r * BCAP];
    for (int i = lo + t; i < hi; i += 256) {
        const unsigned int u = B[i];
        const unsigned int pos = atomicAdd(&lb[u & 0xFFFu], 1u);
        einc[pos] = (int)(u >> 12);
    }
}

// ============ xw = x @ W : W fully LDS-resident, x streamed via registers ==
// 256 thr; thread = (rowg = t>>3)*4 rows x (cg = (t&7)*8) cols. 128 rows/blk.
// No inner barriers; x double-buffered in registers (float4 along k).
__global__ __launch_bounds__(256) void k_gemm(const float* __restrict__ x,
                                              const float* __restrict__ W,
                                              float* __restrict__ xw) {
    __shared__ __align__(16) float Wl[NFEAT * NCLASS];   // 64 KB
    const int t = threadIdx.x;
    {
        const float4* src = (const float4*)W;
        float4* dst = (float4*)Wl;
        #pragma unroll
        for (int i = 0; i < 16; ++i)
            dst[t + i * 256] = src[t + i * 256];
    }
    __syncthreads();

    const int rowg = t >> 3;
    const int cg   = (t & 7) * 8;
    const int r0   = blockIdx.x * 128 + rowg * 4;

    float acc[4][8] = {};
    float4 xa[4];
    #pragma unroll
    for (int i = 0; i < 4; ++i)
        xa[i] = (r0 + i < N_NODES) ? *(const float4*)&x[(size_t)(r0 + i) * NFEAT]
                                   : make_float4(0.f, 0.f, 0.f, 0.f);

    for (int k0 = 0; k0 < NFEAT; k0 += 4) {
        float4 xb[4];
        const int k1 = k0 + 4;
        #pragma unroll
        for (int i = 0; i < 4; ++i) {
            if (k1 < NFEAT && r0 + i < N_NODES)
                xb[i] = *(const float4*)&x[(size_t)(r0 + i) * NFEAT + k1];
            else
                xb[i] = make_float4(0.f, 0.f, 0.f, 0.f);
        }
        #pragma unroll
        for (int kk = 0; kk < 4; ++kk) {
            const float4 w0 = *(const float4*)&Wl[(k0 + kk) * NCLASS + cg];
            const float4 w1 = *(const float4*)&Wl[(k0 + kk) * NCLASS + cg + 4];
            const float wv[8] = {w0.x, w0.y, w0.z, w0.w, w1.x, w1.y, w1.z, w1.w};
            #pragma unroll
            for (int i = 0; i < 4; ++i) {
                const float xs1 = (kk == 0) ? xa[i].x : (kk == 1) ? xa[i].y
                                : (kk == 2) ? xa[i].z : xa[i].w;
                #pragma unroll
                for (int j = 0; j < 8; ++j)
                    acc[i][j] = fmaf(xs1, wv[j], acc[i][j]);
            }
        }
        #pragma unroll
        for (int i = 0; i < 4; ++i) xa[i] = xb[i];
    }

    #pragma unroll
    for (int i = 0; i < 4; ++i) {
        if (r0 + i < N_NODES) {
            float4 o0 = make_float4(acc[i][0], acc[i][1], acc[i][2], acc[i][3]);
            float4 o1 = make_float4(acc[i][4], acc[i][5], acc[i][6], acc[i][7]);
            *(float4*)&xw[(size_t)(r0 + i) * NCLASS + cg]     = o0;
            *(float4*)&xw[(size_t)(r0 + i) * NCLASS + cg + 4] = o1;
        }
    }
}

// ============ per-edge pull gather (one wave per edge, lane=channel) =======
__global__ __launch_bounds__(256) void k_edge_gather(const int* __restrict__ einc,
                                                     const int* __restrict__ eoff,
                                                     const int* __restrict__ ecnt,
                                                     const float* __restrict__ xw,
                                                     float* __restrict__ e_feat) {
    const int wave = (blockIdx.x * 256 + threadIdx.x) >> 6;
    const int lane = threadIdx.x & 63;
    if (wave >= N_EDGES) return;
    const int idx  = (wave & 7) * ELOC + (wave >> 3);   // range-major perm
    const int base = eoff[idx];
    const int deg  = ecnt[idx];
    float a0 = 0.f, a1 = 0.f, a2 = 0.f, a3 = 0.f;
    int j = base;
    const int end = base + deg;
    for (; j + 4 <= end; j += 4) {
        const int n0 = einc[j], n1 = einc[j + 1], n2 = einc[j + 2], n3 = einc[j + 3];
        a0 += xw[(size_t)n0 * NCLASS + lane];
        a1 += xw[(size_t)n1 * NCLASS + lane];
        a2 += xw[(size_t)n2 * NCLASS + lane];
        a3 += xw[(size_t)n3 * NCLASS + lane];
    }
    for (; j < end; ++j) a0 += xw[(size_t)einc[j] * NCLASS + lane];
    const float s = (a0 + a1) + (a2 + a3);
    e_feat[(size_t)wave * NCLASS + lane] = (deg > 0) ? s / (float)deg : 0.f;
}

// ============ per-node pull gather + Dinv + bias + relu ====================
__global__ __launch_bounds__(256) void k_node_gather(const unsigned short* __restrict__ ninc,
                                                     const int* __restrict__ noff,
                                                     const int* __restrict__ ncnt,
                                                     const float* __restrict__ e_feat,
                                                     const float* __restrict__ b,
                                                     float* __restrict__ out) {
    const int wave = (blockIdx.x * 256 + threadIdx.x) >> 6;
    const int lane = threadIdx.x & 63;
    if (wave >= N_NODES) return;
    const int idx  = (wave & 7) * NLOC + (wave >> 3);   // range-major perm
    const int base = noff[idx];
    const int deg  = ncnt[idx];
    float a0 = 0.f, a1 = 0.f, a2 = 0.f, a3 = 0.f;
    int j = base;
    const int end = base + deg;
    for (; j + 4 <= end; j += 4) {
        const int e0 = ninc[j], e1 = ninc[j + 1], e2 = ninc[j + 2], e3 = ninc[j + 3];
        a0 += e_feat[(size_t)e0 * NCLASS + lane];
        a1 += e_feat[(size_t)e1 * NCLASS + lane];
        a2 += e_feat[(size_t)e2 * NCLASS + lane];
        a3 += e_feat[(size_t)e3 * NCLASS + lane];
    }
    for (; j < end; ++j) a0 += e_feat[(size_t)ninc[j] * NCLASS + lane];
    const float s = (a0 + a1) + (a2 + a3);
    const float r = (deg > 0) ? s / (float)deg : 0.f;
    out[(size_t)wave * NCLASS + lane] = fmaxf(r + b[lane], 0.f);
}

extern "C" void kernel_launch(void* const* d_in, const int* in_sizes, int n_in,
                              void* d_out, int out_size, void* d_ws, size_t ws_size,
                              hipStream_t stream) {
    const float* x    = (const float*)d_in[0];
    const int*   adj  = (const int*)d_in[1];
    const float* W    = (const float*)d_in[2];
    const float* bias = (const float*)d_in[3];
    const int* nidx = adj;            // adj[0]: node index per incidence
    const int* eidx = adj + N_INC;    // adj[1]: edge index per incidence
    float* out = (float*)d_out;

    // ---- workspace layout (18,990,656 bytes max-live) ----
    char* ws = (char*)d_ws;
    unsigned int*   ebkt  = (unsigned int*)(ws);                    // 6,455,296
    unsigned int*   nbkt  = (unsigned int*)(ws + 6455296);          // 6,455,296
    unsigned short* ninc  = (unsigned short*)(ws + 12910592);       // 3,200,000
    unsigned short* nhist = (unsigned short*)(ws + 16110592);       // 1,600,000
    unsigned short* ehist = (unsigned short*)(ws + 17710592);       //   320,000
    int* ncnt = (int*)(ws + 18030592);                              //   400,000
    int* noff = (int*)(ws + 18430592);                              //   400,000
    int* ecnt = (int*)(ws + 18830592);                              //    80,000
    int* eoff = (int*)(ws + 18910592);                              //    80,000
    int* bcur = (int*)(ws + 18990592);                              //        64
    // overlays (dead regions at go-live time):
    int*   einc   = (int*)(ws + 6455296);   // over nbkt (dead after k_fill3n)
    float* e_feat = (float*)(ws);           // over ebkt (dead after k_fill3e)

    // zero bucket cursors only
    hipMemsetAsync(bcur, 0, 64, stream);

    // phase 1: bucket split (bulk reservation, no per-incidence atomics)
    k_bucket<<<(N_INC + 1023) / 1024, 256, 0, stream>>>(nidx, eidx, ebkt, nbkt, bcur);

    // phase 2: per-block LDS histograms (zero device atomics)
    k_hist<<<8 * EPB, 256, ELOC * 4, stream>>>(ebkt, bcur, 0, ehist, ELOC, 0xFFFu);
    k_hist<<<8 * EPB, 256, NLOC * 4, stream>>>(nbkt, bcur, 8, nhist, NLOC, 0x3FFFu);

    // phase 3: per-counter block-prefix + degree totals, then global offsets
    k_colscan<<<(8 * ELOC + 255) / 256, 256, 0, stream>>>(ehist, ecnt, ELOC);
    k_colscan<<<(8 * NLOC + 255) / 256, 256, 0, stream>>>(nhist, ncnt, NLOC);
    k_scan<<<1, 1024, 0, stream>>>(ecnt, eoff, N_EDGES);
    k_scan<<<1, 1024, 0, stream>>>(ncnt, noff, N_NODES);

    // phase 4: atomic-free CSR fills (node side first, einc overlays nbkt)
    k_fill3n<<<8 * EPB, 256, 0, stream>>>(nbkt, bcur, nhist, noff, ninc);
    k_fill3e<<<8 * EPB, 256, 0, stream>>>(ebkt, bcur, ehist, eoff, einc);

    // xw = x @ W  (stored in d_out; consumed before out is overwritten)
    k_gemm<<<(N_NODES + 127) / 128, 256, 0, stream>>>(x, W, out);

    // edge aggregation (pull), fused * Binv   (e_feat overlays ebkt)
    k_edge_gather<<<(N_EDGES * 64) / 256, 256, 0, stream>>>(einc, eoff, ecnt, out, e_feat);

    // node aggregation (pull), fused * Dinv + bias + relu
    k_node_gather<<<(N_NODES * 64) / 256, 256, 0, stream>>>(ninc, noff, ncnt, e_feat, bias, out);
}

// Round 8
// 546.286 us; speedup vs baseline: 1.0131x; 1.0131x over previous
//
#include <hip/hip_runtime.h>

#define N_NODES 100000
#define N_EDGES 20000
#define N_INC   1600000
#define NFEAT   256
#define NCLASS  64

#define ELOC 2500            // edges per range (e&7)
#define NLOC 12500           // nodes per range (n&7)
#define BCAP 201728          // per-bucket capacity (mean 200K + ~4 sigma, 64B-aligned)
#define EPB  8               // blocks per bucket in hist/fill
#define LCAP 192             // per-block LDS staging per bucket in k_bucket

typedef int v4i __attribute__((ext_vector_type(4)));

// ============ phase 1: split incidences into 8 edge- and 8 node-buckets ====
// edge-bucket (key e&7): payload (n<<12)|(e>>3)   n:17b, e>>3:12b
// node-bucket (key n&7): payload (e<<14)|(n>>3)   e:15b, n>>3:14b
// Only bulk cursor reservation atomics (~25K total), no histograms.
__global__ __launch_bounds__(256) void k_bucket(const int* __restrict__ nidx,
                                                const int* __restrict__ eidx,
                                                unsigned int* __restrict__ ebkt,
                                                unsigned int* __restrict__ nbkt,
                                                int* __restrict__ bcur) {
    __shared__ unsigned int stage[16][LCAP];
    __shared__ int lcnt[16];
    __shared__ int gbase[16];
    const int t = threadIdx.x;
    if (t < 16) lcnt[t] = 0;
    __syncthreads();

    const int base = blockIdx.x * 1024 + t * 4;
    if (base < N_INC) {
        const v4i e4 = __builtin_nontemporal_load((const v4i*)&eidx[base]);
        const v4i n4 = __builtin_nontemporal_load((const v4i*)&nidx[base]);
        const int es[4] = {e4.x, e4.y, e4.z, e4.w};
        const int ns[4] = {n4.x, n4.y, n4.z, n4.w};
        #pragma unroll
        for (int q = 0; q < 4; ++q) {
            const int e = es[q], n = ns[q];
            {
                const int b = e & 7;
                const unsigned int pay = ((unsigned int)n << 12) | (unsigned int)(e >> 3);
                const int pos = atomicAdd(&lcnt[b], 1);
                if (pos < LCAP) stage[b][pos] = pay;
                else ebkt[(size_t)b * BCAP + atomicAdd(&bcur[b], 1)] = pay;
            }
            {
                const int b = 8 + (n & 7);
                const unsigned int pay = ((unsigned int)e << 14) | (unsigned int)(n >> 3);
                const int pos = atomicAdd(&lcnt[b], 1);
                if (pos < LCAP) stage[b][pos] = pay;
                else nbkt[(size_t)(b - 8) * BCAP + atomicAdd(&bcur[b], 1)] = pay;
            }
        }
    }
    __syncthreads();
    if (t < 16) gbase[t] = atomicAdd(&bcur[t], min(lcnt[t], LCAP));
    __syncthreads();
    #pragma unroll 1
    for (int k = 0; k < 16; ++k) {
        const int cnt = min(lcnt[k], LCAP);
        const int gb  = gbase[k];
        unsigned int* dst = (k < 8) ? &ebkt[(size_t)k * BCAP]
                                    : &nbkt[(size_t)(k - 8) * BCAP];
        for (int i = t; i < cnt; i += 256) dst[gb + i] = stage[k][i];
    }
}

// ============ per-(bucket,block) LDS histogram → u16 per-block hists =======
__global__ __launch_bounds__(256) void k_hist(const unsigned int* __restrict__ bkt,
                                              const int* __restrict__ bcur,
                                              int cur_off,
                                              unsigned short* __restrict__ hist,
                                              int SZ, unsigned int mask) {
    extern __shared__ unsigned int h[];
    const int r = blockIdx.x & 7, b = blockIdx.x >> 3;
    const int t = threadIdx.x;
    for (int i = t; i < SZ; i += 256) h[i] = 0;
    __syncthreads();
    const int cnt = bcur[cur_off + r];
    const int sz  = (cnt + EPB - 1) / EPB;
    const int lo  = b * sz, hi = min(lo + sz, cnt);
    const unsigned int* B = &bkt[(size_t)r * BCAP];
    for (int i = lo + t; i < hi; i += 256)
        atomicAdd(&h[B[i] & mask], 1u);
    __syncthreads();
    unsigned short* H = &hist[(size_t)(r * EPB + b) * SZ];
    for (int i = t; i < SZ; i += 256) H[i] = (unsigned short)h[i];
}

// ============ per-counter exclusive prefix over the EPB block hists ========
__global__ __launch_bounds__(256) void k_colscan(unsigned short* __restrict__ hist,
                                                 int* __restrict__ cnt_perm, int SZ) {
    const int g = blockIdx.x * 256 + threadIdx.x;
    if (g >= 8 * SZ) return;
    const int r = g / SZ, i = g - r * SZ;
    unsigned short* H = hist + (size_t)r * EPB * SZ + i;
    unsigned int run = 0;
    #pragma unroll
    for (int b = 0; b < EPB; ++b) {
        const unsigned int v = H[(size_t)b * SZ];
        H[(size_t)b * SZ] = (unsigned short)run;
        run += v;
    }
    cnt_perm[g] = (int)run;
}

// ============ single-block exclusive scan (int4), offsets only =============
__global__ __launch_bounds__(1024) void k_scan(const int* __restrict__ cnt,
                                               int* __restrict__ off, int n) {
    __shared__ int part[1024];
    const int t = threadIdx.x;
    const int chunk = ((n / 4 + 1023) / 1024) * 4;
    const int lo = min(t * chunk, n);
    const int hi = min(lo + chunk, n);
    int s = 0;
    for (int i = lo; i < hi; i += 4) {
        const int4 v = *(const int4*)&cnt[i];
        s += v.x + v.y + v.z + v.w;
    }
    part[t] = s;
    __syncthreads();
    for (int d = 1; d < 1024; d <<= 1) {
        int v = (t >= d) ? part[t - d] : 0;
        __syncthreads();
        part[t] += v;
        __syncthreads();
    }
    int run = (t == 0) ? 0 : part[t - 1];
    for (int i = lo; i < hi; i += 4) {
        const int4 v = *(const int4*)&cnt[i];
        int4 o;
        o.x = run; run += v.x;
        o.y = run; run += v.y;
        o.z = run; run += v.z;
        o.w = run; run += v.w;
        *(int4*)&off[i] = o;
    }
}

// ============ fills: LDS cursors = off + per-block prefix; LDS atomics only
__global__ __launch_bounds__(256) void k_fill3n(const unsigned int* __restrict__ nbkt,
                                                const int* __restrict__ bcur,
                                                const unsigned short* __restrict__ nhist,
                                                const int* __restrict__ noff,
                                                unsigned short* __restrict__ ninc) {
    __shared__ unsigned int lb[NLOC];
    const int r = blockIdx.x & 7, b = blockIdx.x >> 3;
    const int t = threadIdx.x;
    const unsigned short* H = &nhist[(size_t)(r * EPB + b) * NLOC];
    const int* O = &noff[r * NLOC];
    for (int i = t; i < NLOC; i += 256) lb[i] = (unsigned int)O[i] + H[i];
    __syncthreads();
    const int cnt = bcur[8 + r];
    const int sz  = (cnt + EPB - 1) / EPB;
    const int lo  = b * sz, hi = min(lo + sz, cnt);
    const unsigned int* B = &nbkt[(size_t)r * BCAP];
    for (int i = lo + t; i < hi; i += 256) {
        const unsigned int u = B[i];
        const unsigned int pos = atomicAdd(&lb[u & 0x3FFFu], 1u);
        ninc[pos] = (unsigned short)(u >> 14);
    }
}

__global__ __launch_bounds__(256) void k_fill3e(const unsigned int* __restrict__ ebkt,
                                                const int* __restrict__ bcur,
                                                const unsigned short* __restrict__ ehist,
                                                const int* __restrict__ eoff,
                                                int* __restrict__ einc) {
    __shared__ unsigned int lb[ELOC];
    const int r = blockIdx.x & 7, b = blockIdx.x >> 3;
    const int t = threadIdx.x;
    const unsigned short* H = &ehist[(size_t)(r * EPB + b) * ELOC];
    const int* O = &eoff[r * ELOC];
    for (int i = t; i < ELOC; i += 256) lb[i] = (unsigned int)O[i] + H[i];
    __syncthreads();
    const int cnt = bcur[r];
    const int sz  = (cnt + EPB - 1) / EPB;
    const int lo  = b * sz, hi = min(lo + sz, cnt);
    const unsigned int* B = &ebkt[(size_t)r * BCAP];
    for (int i = lo + t; i < hi; i += 256) {
        const unsigned int u = B[i];
        const unsigned int pos = atomicAdd(&lb[u & 0xFFFu], 1u);
        einc[pos] = (int)(u >> 12);
    }
}

// ============ xw = x @ W : 256-row tile, 8x8 thread-tile, K-chunk 32 =======
// 1.0 FMA per LDS byte (CU balance point). xsT pad 260: reads 2-way (free),
// transposed writes 4-way. W chunk 8KB. LDS total 41.3KB -> 3 blocks/CU.
__global__ __launch_bounds__(256) void k_gemm(const float* __restrict__ x,
                                              const float* __restrict__ W,
                                              float* __restrict__ xw) {
    __shared__ __align__(16) float xsT[32][260];
    __shared__ __align__(16) float Wl[32][64];
    const int t  = threadIdx.x;
    const int tr = t >> 3;          // 0..31 -> rows 8*tr .. 8*tr+7
    const int tc = (t & 7) * 8;     // col group of 8
    const int r0 = blockIdx.x * 256;
    const int q  = t & 7;           // staging: float4 id within 32-k chunk

    float acc[8][8] = {};

    for (int k0 = 0; k0 < NFEAT; k0 += 32) {
        // stage W chunk (32x64 = 512 float4, 2/thread, contiguous)
        {
            const float4* src = (const float4*)&W[(size_t)k0 * NCLASS];
            float4* dst = (float4*)&Wl[0][0];
            dst[t]       = src[t];
            dst[t + 256] = src[t + 256];
        }
        // stage x chunk transposed: thread reads rows (t>>3)+32*it, 16B each
        #pragma unroll
        for (int it = 0; it < 8; ++it) {
            const int row  = (t >> 3) + it * 32;
            const int grow = r0 + row;
            float4 v = make_float4(0.f, 0.f, 0.f, 0.f);
            if (grow < N_NODES)
                v = *(const float4*)&x[(size_t)grow * NFEAT + k0 + q * 4];
            xsT[q * 4 + 0][row] = v.x;
            xsT[q * 4 + 1][row] = v.y;
            xsT[q * 4 + 2][row] = v.z;
            xsT[q * 4 + 3][row] = v.w;
        }
        __syncthreads();

        #pragma unroll
        for (int kk = 0; kk < 32; ++kk) {
            float xv[8], wv[8];
            *(float4*)&xv[0] = *(const float4*)&xsT[kk][tr * 8];
            *(float4*)&xv[4] = *(const float4*)&xsT[kk][tr * 8 + 4];
            *(float4*)&wv[0] = *(const float4*)&Wl[kk][tc];
            *(float4*)&wv[4] = *(const float4*)&Wl[kk][tc + 4];
            #pragma unroll
            for (int i = 0; i < 8; ++i)
                #pragma unroll
                for (int j = 0; j < 8; ++j)
                    acc[i][j] = fmaf(xv[i], wv[j], acc[i][j]);
        }
        __syncthreads();
    }

    #pragma unroll
    for (int i = 0; i < 8; ++i) {
        const int r = r0 + tr * 8 + i;
        if (r < N_NODES) {
            *(float4*)&xw[(size_t)r * NCLASS + tc]     = *(float4*)&acc[i][0];
            *(float4*)&xw[(size_t)r * NCLASS + tc + 4] = *(float4*)&acc[i][4];
        }
    }
}

// ============ per-edge pull gather (one wave per edge, lane=channel) =======
__global__ __launch_bounds__(256) void k_edge_gather(const int* __restrict__ einc,
                                                     const int* __restrict__ eoff,
                                                     const int* __restrict__ ecnt,
                                                     const float* __restrict__ xw,
                                                     float* __restrict__ e_feat) {
    const int wave = (blockIdx.x * 256 + threadIdx.x) >> 6;
    const int lane = threadIdx.x & 63;
    if (wave >= N_EDGES) return;
    const int idx  = (wave & 7) * ELOC + (wave >> 3);   // range-major perm
    const int base = eoff[idx];
    const int deg  = ecnt[idx];
    float a0 = 0.f, a1 = 0.f, a2 = 0.f, a3 = 0.f;
    int j = base;
    const int end = base + deg;
    for (; j + 4 <= end; j += 4) {
        const int n0 = einc[j], n1 = einc[j + 1], n2 = einc[j + 2], n3 = einc[j + 3];
        a0 += xw[(size_t)n0 * NCLASS + lane];
        a1 += xw[(size_t)n1 * NCLASS + lane];
        a2 += xw[(size_t)n2 * NCLASS + lane];
        a3 += xw[(size_t)n3 * NCLASS + lane];
    }
    for (; j < end; ++j) a0 += xw[(size_t)einc[j] * NCLASS + lane];
    const float s = (a0 + a1) + (a2 + a3);
    e_feat[(size_t)wave * NCLASS + lane] = (deg > 0) ? s / (float)deg : 0.f;
}

// ============ per-node pull gather + Dinv + bias + relu ====================
__global__ __launch_bounds__(256) void k_node_gather(const unsigned short* __restrict__ ninc,
                                                     const int* __restrict__ noff,
                                                     const int* __restrict__ ncnt,
                                                     const float* __restrict__ e_feat,
                                                     const float* __restrict__ b,
                                                     float* __restrict__ out) {
    const int wave = (blockIdx.x * 256 + threadIdx.x) >> 6;
    const int lane = threadIdx.x & 63;
    if (wave >= N_NODES) return;
    const int idx  = (wave & 7) * NLOC + (wave >> 3);   // range-major perm
    const int base = noff[idx];
    const int deg  = ncnt[idx];
    float a0 = 0.f, a1 = 0.f, a2 = 0.f, a3 = 0.f;
    int j = base;
    const int end = base + deg;
    for (; j + 4 <= end; j += 4) {
        const int e0 = ninc[j], e1 = ninc[j + 1], e2 = ninc[j + 2], e3 = ninc[j + 3];
        a0 += e_feat[(size_t)e0 * NCLASS + lane];
        a1 += e_feat[(size_t)e1 * NCLASS + lane];
        a2 += e_feat[(size_t)e2 * NCLASS + lane];
        a3 += e_feat[(size_t)e3 * NCLASS + lane];
    }
    for (; j < end; ++j) a0 += e_feat[(size_t)ninc[j] * NCLASS + lane];
    const float s = (a0 + a1) + (a2 + a3);
    const float r = (deg > 0) ? s / (float)deg : 0.f;
    out[(size_t)wave * NCLASS + lane] = fmaxf(r + b[lane], 0.f);
}

extern "C" void kernel_launch(void* const* d_in, const int* in_sizes, int n_in,
                              void* d_out, int out_size, void* d_ws, size_t ws_size,
                              hipStream_t stream) {
    const float* x    = (const float*)d_in[0];
    const int*   adj  = (const int*)d_in[1];
    const float* W    = (const float*)d_in[2];
    const float* bias = (const float*)d_in[3];
    const int* nidx = adj;            // adj[0]: node index per incidence
    const int* eidx = adj + N_INC;    // adj[1]: edge index per incidence
    float* out = (float*)d_out;

    // ---- workspace layout (18,990,656 bytes max-live) ----
    char* ws = (char*)d_ws;
    unsigned int*   ebkt  = (unsigned int*)(ws);                    // 6,455,296
    unsigned int*   nbkt  = (unsigned int*)(ws + 6455296);          // 6,455,296
    unsigned short* ninc  = (unsigned short*)(ws + 12910592);       // 3,200,000
    unsigned short* nhist = (unsigned short*)(ws + 16110592);       // 1,600,000
    unsigned short* ehist = (unsigned short*)(ws + 17710592);       //   320,000
    int* ncnt = (int*)(ws + 18030592);                              //   400,000
    int* noff = (int*)(ws + 18430592);                              //   400,000
    int* ecnt = (int*)(ws + 18830592);                              //    80,000
    int* eoff = (int*)(ws + 18910592);                              //    80,000
    int* bcur = (int*)(ws + 18990592);                              //        64
    // overlays (dead regions at go-live time):
    int*   einc   = (int*)(ws + 6455296);   // over nbkt (dead after k_fill3n)
    float* e_feat = (float*)(ws);           // over ebkt (dead after k_fill3e)

    // zero bucket cursors only
    hipMemsetAsync(bcur, 0, 64, stream);

    // phase 1: bucket split (bulk reservation, no per-incidence atomics)
    k_bucket<<<(N_INC + 1023) / 1024, 256, 0, stream>>>(nidx, eidx, ebkt, nbkt, bcur);

    // phase 2: per-block LDS histograms (zero device atomics)
    k_hist<<<8 * EPB, 256, ELOC * 4, stream>>>(ebkt, bcur, 0, ehist, ELOC, 0xFFFu);
    k_hist<<<8 * EPB, 256, NLOC * 4, stream>>>(nbkt, bcur, 8, nhist, NLOC, 0x3FFFu);

    // phase 3: per-counter block-prefix + degree totals, then global offsets
    k_colscan<<<(8 * ELOC + 255) / 256, 256, 0, stream>>>(ehist, ecnt, ELOC);
    k_colscan<<<(8 * NLOC + 255) / 256, 256, 0, stream>>>(nhist, ncnt, NLOC);
    k_scan<<<1, 1024, 0, stream>>>(ecnt, eoff, N_EDGES);
    k_scan<<<1, 1024, 0, stream>>>(ncnt, noff, N_NODES);

    // phase 4: atomic-free CSR fills (node side first, einc overlays nbkt)
    k_fill3n<<<8 * EPB, 256, 0, stream>>>(nbkt, bcur, nhist, noff, ninc);
    k_fill3e<<<8 * EPB, 256, 0, stream>>>(ebkt, bcur, ehist, eoff, einc);

    // xw = x @ W  (stored in d_out; consumed before out is overwritten)
    k_gemm<<<(N_NODES + 255) / 256, 256, 0, stream>>>(x, W, out);

    // edge aggregation (pull), fused * Binv   (e_feat overlays ebkt)
    k_edge_gather<<<(N_EDGES * 64) / 256, 256, 0, stream>>>(einc, eoff, ecnt, out, e_feat);

    // node aggregation (pull), fused * Dinv + bias + relu
    k_node_gather<<<(N_NODES * 64) / 256, 256, 0, stream>>>(ninc, noff, ncnt, e_feat, bias, out);
}

// Round 9
// 511.362 us; speedup vs baseline: 1.0822x; 1.0683x over previous
//
#include <hip/hip_runtime.h>

#define N_NODES 100000
#define N_EDGES 20000
#define N_INC   1600000
#define NFEAT   256
#define NCLASS  64

#define ELOC 2500            // edges per range (e&7)
#define NLOC 12500           // nodes per range (n&7)
#define BCAP 201728          // per-bucket capacity (mean 200K + ~4 sigma, 64B-aligned)
#define EPB  8               // blocks per bucket in hist/fill
#define LCAP 192             // per-block LDS staging per bucket in k_bucket

typedef int v4i __attribute__((ext_vector_type(4)));
typedef __attribute__((ext_vector_type(8))) short bf16x8;
typedef __attribute__((ext_vector_type(4))) float f32x4;

__device__ __forceinline__ unsigned short bf16_rne(float f) {
    unsigned int u = __builtin_bit_cast(unsigned int, f);
    unsigned int r = (u + 0x7FFFu + ((u >> 16) & 1u)) >> 16;
    return (unsigned short)r;
}
__device__ __forceinline__ float bf16_f(unsigned short h) {
    unsigned int u = (unsigned int)h << 16;
    return __builtin_bit_cast(float, u);
}

// ============ phase 1: split incidences into 8 edge- and 8 node-buckets ====
__global__ __launch_bounds__(256) void k_bucket(const int* __restrict__ nidx,
                                                const int* __restrict__ eidx,
                                                unsigned int* __restrict__ ebkt,
                                                unsigned int* __restrict__ nbkt,
                                                int* __restrict__ bcur) {
    __shared__ unsigned int stage[16][LCAP];
    __shared__ int lcnt[16];
    __shared__ int gbase[16];
    const int t = threadIdx.x;
    if (t < 16) lcnt[t] = 0;
    __syncthreads();

    const int base = blockIdx.x * 1024 + t * 4;
    if (base < N_INC) {
        const v4i e4 = __builtin_nontemporal_load((const v4i*)&eidx[base]);
        const v4i n4 = __builtin_nontemporal_load((const v4i*)&nidx[base]);
        const int es[4] = {e4.x, e4.y, e4.z, e4.w};
        const int ns[4] = {n4.x, n4.y, n4.z, n4.w};
        #pragma unroll
        for (int q = 0; q < 4; ++q) {
            const int e = es[q], n = ns[q];
            {
                const int b = e & 7;
                const unsigned int pay = ((unsigned int)n << 12) | (unsigned int)(e >> 3);
                const int pos = atomicAdd(&lcnt[b], 1);
                if (pos < LCAP) stage[b][pos] = pay;
                else ebkt[(size_t)b * BCAP + atomicAdd(&bcur[b], 1)] = pay;
            }
            {
                const int b = 8 + (n & 7);
                const unsigned int pay = ((unsigned int)e << 14) | (unsigned int)(n >> 3);
                const int pos = atomicAdd(&lcnt[b], 1);
                if (pos < LCAP) stage[b][pos] = pay;
                else nbkt[(size_t)(b - 8) * BCAP + atomicAdd(&bcur[b], 1)] = pay;
            }
        }
    }
    __syncthreads();
    if (t < 16) gbase[t] = atomicAdd(&bcur[t], min(lcnt[t], LCAP));
    __syncthreads();
    #pragma unroll 1
    for (int k = 0; k < 16; ++k) {
        const int cnt = min(lcnt[k], LCAP);
        const int gb  = gbase[k];
        unsigned int* dst = (k < 8) ? &ebkt[(size_t)k * BCAP]
                                    : &nbkt[(size_t)(k - 8) * BCAP];
        for (int i = t; i < cnt; i += 256) dst[gb + i] = stage[k][i];
    }
}

// ============ per-(bucket,block) LDS histogram → u16 per-block hists =======
__global__ __launch_bounds__(256) void k_hist(const unsigned int* __restrict__ bkt,
                                              const int* __restrict__ bcur,
                                              int cur_off,
                                              unsigned short* __restrict__ hist,
                                              int SZ, unsigned int mask) {
    extern __shared__ unsigned int h[];
    const int r = blockIdx.x & 7, b = blockIdx.x >> 3;
    const int t = threadIdx.x;
    for (int i = t; i < SZ; i += 256) h[i] = 0;
    __syncthreads();
    const int cnt = bcur[cur_off + r];
    const int sz  = (cnt + EPB - 1) / EPB;
    const int lo  = b * sz, hi = min(lo + sz, cnt);
    const unsigned int* B = &bkt[(size_t)r * BCAP];
    for (int i = lo + t; i < hi; i += 256)
        atomicAdd(&h[B[i] & mask], 1u);
    __syncthreads();
    unsigned short* H = &hist[(size_t)(r * EPB + b) * SZ];
    for (int i = t; i < SZ; i += 256) H[i] = (unsigned short)h[i];
}

// ============ per-counter exclusive prefix over the EPB block hists ========
__global__ __launch_bounds__(256) void k_colscan(unsigned short* __restrict__ hist,
                                                 int* __restrict__ cnt_perm, int SZ) {
    const int g = blockIdx.x * 256 + threadIdx.x;
    if (g >= 8 * SZ) return;
    const int r = g / SZ, i = g - r * SZ;
    unsigned short* H = hist + (size_t)r * EPB * SZ + i;
    unsigned int run = 0;
    #pragma unroll
    for (int b = 0; b < EPB; ++b) {
        const unsigned int v = H[(size_t)b * SZ];
        H[(size_t)b * SZ] = (unsigned short)run;
        run += v;
    }
    cnt_perm[g] = (int)run;
}

// ============ single-block exclusive scan (int4), offsets only =============
__global__ __launch_bounds__(1024) void k_scan(const int* __restrict__ cnt,
                                               int* __restrict__ off, int n) {
    __shared__ int part[1024];
    const int t = threadIdx.x;
    const int chunk = ((n / 4 + 1023) / 1024) * 4;
    const int lo = min(t * chunk, n);
    const int hi = min(lo + chunk, n);
    int s = 0;
    for (int i = lo; i < hi; i += 4) {
        const int4 v = *(const int4*)&cnt[i];
        s += v.x + v.y + v.z + v.w;
    }
    part[t] = s;
    __syncthreads();
    for (int d = 1; d < 1024; d <<= 1) {
        int v = (t >= d) ? part[t - d] : 0;
        __syncthreads();
        part[t] += v;
        __syncthreads();
    }
    int run = (t == 0) ? 0 : part[t - 1];
    for (int i = lo; i < hi; i += 4) {
        const int4 v = *(const int4*)&cnt[i];
        int4 o;
        o.x = run; run += v.x;
        o.y = run; run += v.y;
        o.z = run; run += v.z;
        o.w = run; run += v.w;
        *(int4*)&off[i] = o;
    }
}

// ============ fills: LDS cursors = off + per-block prefix; LDS atomics only
__global__ __launch_bounds__(256) void k_fill3n(const unsigned int* __restrict__ nbkt,
                                                const int* __restrict__ bcur,
                                                const unsigned short* __restrict__ nhist,
                                                const int* __restrict__ noff,
                                                unsigned short* __restrict__ ninc) {
    __shared__ unsigned int lb[NLOC];
    const int r = blockIdx.x & 7, b = blockIdx.x >> 3;
    const int t = threadIdx.x;
    const unsigned short* H = &nhist[(size_t)(r * EPB + b) * NLOC];
    const int* O = &noff[r * NLOC];
    for (int i = t; i < NLOC; i += 256) lb[i] = (unsigned int)O[i] + H[i];
    __syncthreads();
    const int cnt = bcur[8 + r];
    const int sz  = (cnt + EPB - 1) / EPB;
    const int lo  = b * sz, hi = min(lo + sz, cnt);
    const unsigned int* B = &nbkt[(size_t)r * BCAP];
    for (int i = lo + t; i < hi; i += 256) {
        const unsigned int u = B[i];
        const unsigned int pos = atomicAdd(&lb[u & 0x3FFFu], 1u);
        ninc[pos] = (unsigned short)(u >> 14);
    }
}

__global__ __launch_bounds__(256) void k_fill3e(const unsigned int* __restrict__ ebkt,
                                                const int* __restrict__ bcur,
                                                const unsigned short* __restrict__ ehist,
                                                const int* __restrict__ eoff,
                                                int* __restrict__ einc) {
    __shared__ unsigned int lb[ELOC];
    const int r = blockIdx.x & 7, b = blockIdx.x >> 3;
    const int t = threadIdx.x;
    const unsigned short* H = &ehist[(size_t)(r * EPB + b) * ELOC];
    const int* O = &eoff[r * ELOC];
    for (int i = t; i < ELOC; i += 256) lb[i] = (unsigned int)O[i] + H[i];
    __syncthreads();
    const int cnt = bcur[r];
    const int sz  = (cnt + EPB - 1) / EPB;
    const int lo  = b * sz, hi = min(lo + sz, cnt);
    const unsigned int* B = &ebkt[(size_t)r * BCAP];
    for (int i = lo + t; i < hi; i += 256) {
        const unsigned int u = B[i];
        const unsigned int pos = atomicAdd(&lb[u & 0xFFFu], 1u);
        einc[pos] = (int)(u >> 12);
    }
}

// ============ W pre-split: wt_h/wt_l[c][k] bf16 (transposed), once =========
__global__ __launch_bounds__(256) void k_wsplit(const float* __restrict__ W,
                                                unsigned short* __restrict__ wt_h,
                                                unsigned short* __restrict__ wt_l) {
    const int i = blockIdx.x * 256 + threadIdx.x;   // i over 256*64
    if (i >= NFEAT * NCLASS) return;
    const int k = i >> 6, c = i & 63;
    const float w = W[i];
    const unsigned short h = bf16_rne(w);
    wt_h[c * NFEAT + k] = h;
    wt_l[c * NFEAT + k] = bf16_rne(w - bf16_f(h));
}

// ============ xw = x @ W via split-bf16 MFMA =============================
// 128-row tile, 4 waves; wave = 2 row-tiles x 4 col-tiles of 16x16x32 mfma.
// 3 products: Ah*Bh + Ah*Bl + Al*Bh (Al*Bl ~2^-18, dropped).
// LDS rows padded to 40 (stride 80B) -> 2-way (free) b128 frag reads.
__global__ __launch_bounds__(256) void k_gemm(const float* __restrict__ x,
                                              const unsigned short* __restrict__ wt_h,
                                              const unsigned short* __restrict__ wt_l,
                                              float* __restrict__ xw) {
    __shared__ unsigned short xh[128][40], xl[128][40];
    __shared__ unsigned short wh[64][40],  wl[64][40];
    const int t = threadIdx.x;
    const int wave = t >> 6, lane = t & 63;
    const int r0 = blockIdx.x * 128;
    const int fr = lane & 15, fs = lane >> 4;

    f32x4 acc[2][4] = {};

    for (int k0 = 0; k0 < NFEAT; k0 += 32) {
        // stage x chunk (128 x 32 f32 -> bf16 hi/lo)
        #pragma unroll
        for (int it = 0; it < 4; ++it) {
            const int s = t + it * 256;
            const int row = s >> 3, q = s & 7;
            const int gr = r0 + row;
            float4 v = make_float4(0.f, 0.f, 0.f, 0.f);
            if (gr < N_NODES)
                v = *(const float4*)&x[(size_t)gr * NFEAT + k0 + q * 4];
            ushort4 h, l;
            h.x = bf16_rne(v.x); l.x = bf16_rne(v.x - bf16_f(h.x));
            h.y = bf16_rne(v.y); l.y = bf16_rne(v.y - bf16_f(h.y));
            h.z = bf16_rne(v.z); l.z = bf16_rne(v.z - bf16_f(h.z));
            h.w = bf16_rne(v.w); l.w = bf16_rne(v.w - bf16_f(h.w));
            *(ushort4*)&xh[row][q * 4] = h;
            *(ushort4*)&xl[row][q * 4] = l;
        }
        // stage W chunk (64 x 32 bf16 hi/lo, pre-transposed in global)
        #pragma unroll
        for (int it = 0; it < 2; ++it) {
            const int s = t + it * 256;          // < 512
            const int c = s >> 3, q = s & 7;
            *(ushort4*)&wh[c][q * 4] = *(const ushort4*)&wt_h[c * NFEAT + k0 + q * 4];
            *(ushort4*)&wl[c][q * 4] = *(const ushort4*)&wt_l[c * NFEAT + k0 + q * 4];
        }
        __syncthreads();

        bf16x8 a_h[2], a_l[2], b_h[4], b_l[4];
        #pragma unroll
        for (int rt = 0; rt < 2; ++rt) {
            const int row = wave * 32 + rt * 16 + fr;
            a_h[rt] = *(const bf16x8*)&xh[row][fs * 8];
            a_l[rt] = *(const bf16x8*)&xl[row][fs * 8];
        }
        #pragma unroll
        for (int ct = 0; ct < 4; ++ct) {
            const int c = ct * 16 + fr;
            b_h[ct] = *(const bf16x8*)&wh[c][fs * 8];
            b_l[ct] = *(const bf16x8*)&wl[c][fs * 8];
        }
        #pragma unroll
        for (int rt = 0; rt < 2; ++rt)
            #pragma unroll
            for (int ct = 0; ct < 4; ++ct) {
                acc[rt][ct] = __builtin_amdgcn_mfma_f32_16x16x32_bf16(
                    a_h[rt], b_h[ct], acc[rt][ct], 0, 0, 0);
                acc[rt][ct] = __builtin_amdgcn_mfma_f32_16x16x32_bf16(
                    a_h[rt], b_l[ct], acc[rt][ct], 0, 0, 0);
                acc[rt][ct] = __builtin_amdgcn_mfma_f32_16x16x32_bf16(
                    a_l[rt], b_h[ct], acc[rt][ct], 0, 0, 0);
            }
        __syncthreads();
    }

    // C/D layout: col = lane&15, row = (lane>>4)*4 + reg  [verified mapping]
    #pragma unroll
    for (int rt = 0; rt < 2; ++rt) {
        const int grb = r0 + wave * 32 + rt * 16 + (lane >> 4) * 4;
        #pragma unroll
        for (int ct = 0; ct < 4; ++ct) {
            const int c = ct * 16 + (lane & 15);
            #pragma unroll
            for (int reg = 0; reg < 4; ++reg) {
                const int gr = grb + reg;
                if (gr < N_NODES) xw[(size_t)gr * NCLASS + c] = acc[rt][ct][reg];
            }
        }
    }
}

// ============ per-edge pull gather (one wave per edge, lane=channel) =======
__global__ __launch_bounds__(256) void k_edge_gather(const int* __restrict__ einc,
                                                     const int* __restrict__ eoff,
                                                     const int* __restrict__ ecnt,
                                                     const float* __restrict__ xw,
                                                     float* __restrict__ e_feat) {
    const int wave = (blockIdx.x * 256 + threadIdx.x) >> 6;
    const int lane = threadIdx.x & 63;
    if (wave >= N_EDGES) return;
    const int idx  = (wave & 7) * ELOC + (wave >> 3);   // range-major perm
    const int base = eoff[idx];
    const int deg  = ecnt[idx];
    float a0 = 0.f, a1 = 0.f, a2 = 0.f, a3 = 0.f;
    int j = base;
    const int end = base + deg;
    for (; j + 4 <= end; j += 4) {
        const int n0 = einc[j], n1 = einc[j + 1], n2 = einc[j + 2], n3 = einc[j + 3];
        a0 += xw[(size_t)n0 * NCLASS + lane];
        a1 += xw[(size_t)n1 * NCLASS + lane];
        a2 += xw[(size_t)n2 * NCLASS + lane];
        a3 += xw[(size_t)n3 * NCLASS + lane];
    }
    for (; j < end; ++j) a0 += xw[(size_t)einc[j] * NCLASS + lane];
    const float s = (a0 + a1) + (a2 + a3);
    e_feat[(size_t)wave * NCLASS + lane] = (deg > 0) ? s / (float)deg : 0.f;
}

// ============ per-node pull gather + Dinv + bias + relu ====================
__global__ __launch_bounds__(256) void k_node_gather(const unsigned short* __restrict__ ninc,
                                                     const int* __restrict__ noff,
                                                     const int* __restrict__ ncnt,
                                                     const float* __restrict__ e_feat,
                                                     const float* __restrict__ b,
                                                     float* __restrict__ out) {
    const int wave = (blockIdx.x * 256 + threadIdx.x) >> 6;
    const int lane = threadIdx.x & 63;
    if (wave >= N_NODES) return;
    const int idx  = (wave & 7) * NLOC + (wave >> 3);   // range-major perm
    const int base = noff[idx];
    const int deg  = ncnt[idx];
    float a0 = 0.f, a1 = 0.f, a2 = 0.f, a3 = 0.f;
    int j = base;
    const int end = base + deg;
    for (; j + 4 <= end; j += 4) {
        const int e0 = ninc[j], e1 = ninc[j + 1], e2 = ninc[j + 2], e3 = ninc[j + 3];
        a0 += e_feat[(size_t)e0 * NCLASS + lane];
        a1 += e_feat[(size_t)e1 * NCLASS + lane];
        a2 += e_feat[(size_t)e2 * NCLASS + lane];
        a3 += e_feat[(size_t)e3 * NCLASS + lane];
    }
    for (; j < end; ++j) a0 += e_feat[(size_t)ninc[j] * NCLASS + lane];
    const float s = (a0 + a1) + (a2 + a3);
    const float r = (deg > 0) ? s / (float)deg : 0.f;
    out[(size_t)wave * NCLASS + lane] = fmaxf(r + b[lane], 0.f);
}

extern "C" void kernel_launch(void* const* d_in, const int* in_sizes, int n_in,
                              void* d_out, int out_size, void* d_ws, size_t ws_size,
                              hipStream_t stream) {
    const float* x    = (const float*)d_in[0];
    const int*   adj  = (const int*)d_in[1];
    const float* W    = (const float*)d_in[2];
    const float* bias = (const float*)d_in[3];
    const int* nidx = adj;            // adj[0]: node index per incidence
    const int* eidx = adj + N_INC;    // adj[1]: edge index per incidence
    float* out = (float*)d_out;

    // ---- workspace layout (19,056,192 bytes max-live) ----
    char* ws = (char*)d_ws;
    unsigned int*   ebkt  = (unsigned int*)(ws);                    // 6,455,296
    unsigned int*   nbkt  = (unsigned int*)(ws + 6455296);          // 6,455,296
    unsigned short* ninc  = (unsigned short*)(ws + 12910592);       // 3,200,000
    unsigned short* nhist = (unsigned short*)(ws + 16110592);       // 1,600,000
    unsigned short* ehist = (unsigned short*)(ws + 17710592);       //   320,000
    int* ncnt = (int*)(ws + 18030592);                              //   400,000
    int* noff = (int*)(ws + 18430592);                              //   400,000
    int* ecnt = (int*)(ws + 18830592);                              //    80,000
    int* eoff = (int*)(ws + 18910592);                              //    80,000
    int* bcur = (int*)(ws + 18990592);                              //        64
    unsigned short* wt_h = (unsigned short*)(ws + 18990656);        //    32,768
    unsigned short* wt_l = (unsigned short*)(ws + 19023424);        //    32,768
    // overlays (dead regions at go-live time):
    int*   einc   = (int*)(ws + 6455296);   // over nbkt (dead after k_fill3n)
    float* e_feat = (float*)(ws);           // over ebkt (dead after k_fill3e)

    // zero bucket cursors only
    hipMemsetAsync(bcur, 0, 64, stream);

    // W split (tiny, independent)
    k_wsplit<<<(NFEAT * NCLASS + 255) / 256, 256, 0, stream>>>(W, wt_h, wt_l);

    // phase 1: bucket split (bulk reservation, no per-incidence atomics)
    k_bucket<<<(N_INC + 1023) / 1024, 256, 0, stream>>>(nidx, eidx, ebkt, nbkt, bcur);

    // phase 2: per-block LDS histograms (zero device atomics)
    k_hist<<<8 * EPB, 256, ELOC * 4, stream>>>(ebkt, bcur, 0, ehist, ELOC, 0xFFFu);
    k_hist<<<8 * EPB, 256, NLOC * 4, stream>>>(nbkt, bcur, 8, nhist, NLOC, 0x3FFFu);

    // phase 3: per-counter block-prefix + degree totals, then global offsets
    k_colscan<<<(8 * ELOC + 255) / 256, 256, 0, stream>>>(ehist, ecnt, ELOC);
    k_colscan<<<(8 * NLOC + 255) / 256, 256, 0, stream>>>(nhist, ncnt, NLOC);
    k_scan<<<1, 1024, 0, stream>>>(ecnt, eoff, N_EDGES);
    k_scan<<<1, 1024, 0, stream>>>(ncnt, noff, N_NODES);

    // phase 4: atomic-free CSR fills (node side first, einc overlays nbkt)
    k_fill3n<<<8 * EPB, 256, 0, stream>>>(nbkt, bcur, nhist, noff, ninc);
    k_fill3e<<<8 * EPB, 256, 0, stream>>>(ebkt, bcur, ehist, eoff, einc);

    // xw = x @ W  split-bf16 MFMA (stored in d_out; consumed before overwrite)
    k_gemm<<<(N_NODES + 127) / 128, 256, 0, stream>>>(x, wt_h, wt_l, out);

    // edge aggregation (pull), fused * Binv   (e_feat overlays ebkt)
    k_edge_gather<<<(N_EDGES * 64) / 256, 256, 0, stream>>>(einc, eoff, ecnt, out, e_feat);

    // node aggregation (pull), fused * Dinv + bias + relu
    k_node_gather<<<(N_NODES * 64) / 256, 256, 0, stream>>>(ninc, noff, ncnt, e_feat, bias, out);
}